// Round 1
// baseline (62.895 us; speedup 1.0000x reference)
//
#include <hip/hip_runtime.h>

static constexpr int H = 128;
static constexpr int W = 128;
static constexpr int B = 32;

// Phase 1: histogram heights per column, sequential over rows (scan dependency).
// grid = B blocks, block = W threads; thread c handles column c of batch b.
// heights stored as uint8 (max 128). Block 0 also zeroes the output buffer.
__global__ void lr_heights(const float* __restrict__ Y,
                           unsigned char* __restrict__ heights,
                           int* __restrict__ out) {
    const int b = blockIdx.x;
    const int c = threadIdx.x;
    if (b == 0 && c < B) out[c] = 0;           // clean baseline for atomicMax
    const float* y = Y + (size_t)b * H * W;
    unsigned char* hh = heights + (size_t)b * H * W;
    int h = 0;
    #pragma unroll 8
    for (int r = 0; r < H; ++r) {
        float v = y[r * W + c];                 // coalesced: lane c -> addr+4c
        h = (v > 0.5f) ? (h + 1) : 0;
        hh[r * W + c] = (unsigned char)h;
    }
}

// Phase 2: one block per (batch,row). Nearest strictly-smaller left/right via
// LDS scan with early break (== reference's argmax/argmin over k<j / k>j with
// heights[k] < heights[j]), then block max-reduce and atomicMax into out[b].
__global__ void lr_area(const unsigned char* __restrict__ heights,
                        int* __restrict__ out) {
    const int task = blockIdx.x;                // task = b*H + r
    const int b = task >> 7;                    // /H
    const int j = threadIdx.x;
    __shared__ int hrow[W];
    __shared__ int wmax[2];
    const unsigned char* hr = heights + (size_t)task * W;
    const int hj = hr[j];
    hrow[j] = hj;
    __syncthreads();

    int left = -1;
    for (int k = j - 1; k >= 0; --k)
        if (hrow[k] < hj) { left = k; break; }
    int right = W;
    for (int k = j + 1; k < W; ++k)
        if (hrow[k] < hj) { right = k; break; }

    int area = hj * (right - left - 1);

    #pragma unroll
    for (int off = 32; off > 0; off >>= 1)      // 64-lane wave max-reduce
        area = max(area, __shfl_xor(area, off, 64));
    if ((j & 63) == 0) wmax[j >> 6] = area;
    __syncthreads();
    if (j == 0) atomicMax(&out[b], max(wmax[0], wmax[1]));
}

extern "C" void kernel_launch(void* const* d_in, const int* in_sizes, int n_in,
                              void* d_out, int out_size, void* d_ws, size_t ws_size,
                              hipStream_t stream) {
    const float* Y = (const float*)d_in[0];
    int* out = (int*)d_out;
    unsigned char* heights = (unsigned char*)d_ws;   // 32*128*128 = 512 KB

    lr_heights<<<B, W, 0, stream>>>(Y, heights, out);
    lr_area<<<B * H, W, 0, stream>>>(heights, out);
}

// Round 3
// 50.823 us; speedup vs baseline: 1.2375x; 1.2375x over previous
//
#include <hip/hip_runtime.h>

static constexpr int H = 128;
static constexpr int W = 128;
static constexpr int B = 32;

// One block per (batch,row). Heights are recomputed on the fly (upward column
// scan from row r while Y>0.5) -- no workspace, no cross-kernel state.
// Then branch-free all-pairs "strictly less" bitmask (128 bits in two u64),
// nearest-smaller-left/right via clz/ctz, wave max-reduce, one atomicMax.
__global__ __launch_bounds__(W) void lr_fused(const float* __restrict__ Y,
                                              int* __restrict__ out) {
    const int task = blockIdx.x;              // task = b*H + r
    const int b = task >> 7;
    const int r = task & (H - 1);
    const int j = threadIdx.x;
    const float* __restrict__ y = Y + (size_t)b * H * W + j;

    // Height of column j at row r: length of consecutive (>0.5) run ending at r.
    // Random Bernoulli(1/2) data => expected trip ~2, wave-worst ~8; L2-resident.
    int h = 0;
    for (int t = r; t >= 0; --t) {
        if (y[(size_t)t * W] > 0.5f) ++h;
        else break;
    }

    __shared__ unsigned char hrow8[W];
    __shared__ int wmax[2];
    hrow8[j] = (unsigned char)h;              // max 128, fits u8
    __syncthreads();

    const unsigned int hj = (unsigned int)h;
    const unsigned int* __restrict__ hword = (const unsigned int*)hrow8;

    // bit k of (mhi:mlo) set iff h[k] < h[j]; LDS dword reads are wave-uniform
    // broadcasts (zero bank conflicts), fully unrolled and independent.
    unsigned long long mlo = 0ULL, mhi = 0ULL;
    #pragma unroll
    for (int w = 0; w < 16; ++w) {
        const unsigned int x = hword[w];
        #pragma unroll
        for (int t = 0; t < 4; ++t)
            if (((x >> (t * 8)) & 0xFFu) < hj) mlo |= (1ULL << (w * 4 + t));
    }
    #pragma unroll
    for (int w = 16; w < 32; ++w) {
        const unsigned int x = hword[w];
        #pragma unroll
        for (int t = 0; t < 4; ++t)
            if (((x >> (t * 8)) & 0xFFu) < hj) mhi |= (1ULL << ((w - 16) * 4 + t));
    }

    // Nearest strictly-smaller left/right. (2ULL<<63)-1 wraps to all-ones so
    // j==63 / j==127 fall through correctly. The j<64 branch is wave-uniform.
    int left, right;
    if (j < 64) {
        const unsigned long long below = mlo & ((1ULL << j) - 1ULL);
        const unsigned long long above = mlo & ~((2ULL << j) - 1ULL);
        left  = below ? 63 - __builtin_clzll(below) : -1;
        right = above ? __builtin_ctzll(above)
                      : (mhi ? 64 + __builtin_ctzll(mhi) : W);
    } else {
        const int jj = j - 64;
        const unsigned long long below = mhi & ((1ULL << jj) - 1ULL);
        const unsigned long long above = mhi & ~((2ULL << jj) - 1ULL);
        left  = below ? 127 - __builtin_clzll(below)
                      : (mlo ? 63 - __builtin_clzll(mlo) : -1);
        right = above ? 64 + __builtin_ctzll(above) : W;
    }

    int area = (int)hj * (right - left - 1);

    #pragma unroll
    for (int off = 32; off > 0; off >>= 1)    // 64-lane wave max-reduce
        area = max(area, __shfl_xor(area, off, 64));
    if ((j & 63) == 0) wmax[j >> 6] = area;
    __syncthreads();
    if (j == 0) atomicMax(&out[b], max(wmax[0], wmax[1]));
}

extern "C" void kernel_launch(void* const* d_in, const int* in_sizes, int n_in,
                              void* d_out, int out_size, void* d_ws, size_t ws_size,
                              hipStream_t stream) {
    const float* Y = (const float*)d_in[0];
    int* out = (int*)d_out;
    (void)d_ws; (void)ws_size;                 // workspace deliberately unused

    // Captured as a memset node; orders before the kernel on `stream`.
    hipMemsetAsync(out, 0, (size_t)out_size * sizeof(int), stream);
    lr_fused<<<B * H, W, 0, stream>>>(Y, out);
}

// Round 4
// 17.763 us; speedup vs baseline: 3.5407x; 2.8611x over previous
//
#include <hip/hip_runtime.h>

static constexpr int H = 128;
static constexpr int W = 128;
static constexpr int B = 32;

// Phase 1: one block per (batch,row). Height via 32 INDEPENDENT clamped window
// loads (no dependent-load chain); bit k = (row r-k > 0.5); h = ctz(~mask),
// serial fallback only for runs >= 32 (prob ~2^-32 per site on this data).
// Then branch-free all-pairs "strictly less" bitmask -> nearest-smaller
// left/right via clz/ctz -> area -> block max -> ONE non-atomic partial store.
// (use_atomic!=0 is the ws-too-small fallback: atomicMax into out instead.)
__global__ __launch_bounds__(W) void lr_rows(const float* __restrict__ Y,
                                             int* __restrict__ partials,
                                             int* __restrict__ out,
                                             int use_atomic) {
    const int task = blockIdx.x;              // task = b*H + r
    const int b = task >> 7;
    const int r = task & (H - 1);
    const int j = threadIdx.x;
    const float* __restrict__ ycol = Y + (size_t)b * H * W + j;

    // 32 independent loads, coalesced across lanes (lane j -> +4j), row
    // clamped to 0 so all addresses are in-bounds; out-of-window bits zeroed.
    unsigned int mask = 0u;
    #pragma unroll
    for (int k = 0; k < 32; ++k) {
        int t = r - k; t = t < 0 ? 0 : t;
        if (ycol[(size_t)t * W] > 0.5f) mask |= (1u << k);
    }
    if (r < 32) mask &= (2u << r) - 1u;       // r=31: (2u<<31)-1 wraps to ~0u, no-op
    int h;
    if (mask == 0xFFFFFFFFu) {                // run spans whole window (r>=31)
        h = 32;
        int t = r - 32;
        while (t >= 0 && ycol[(size_t)t * W] > 0.5f) { ++h; --t; }
    } else {
        h = __builtin_ctz(~mask);
    }

    __shared__ unsigned char hrow8[W];
    __shared__ int wmax[2];
    hrow8[j] = (unsigned char)h;              // max 128, fits u8
    __syncthreads();

    const unsigned int hj = (unsigned int)h;
    const unsigned int* __restrict__ hword = (const unsigned int*)hrow8;

    // bit k of (mhi:mlo) set iff h[k] < h[j]; LDS dword reads are wave-uniform
    // broadcasts (zero bank conflicts), fully unrolled and independent.
    unsigned long long mlo = 0ULL, mhi = 0ULL;
    #pragma unroll
    for (int w = 0; w < 16; ++w) {
        const unsigned int x = hword[w];
        #pragma unroll
        for (int t = 0; t < 4; ++t)
            if (((x >> (t * 8)) & 0xFFu) < hj) mlo |= (1ULL << (w * 4 + t));
    }
    #pragma unroll
    for (int w = 16; w < 32; ++w) {
        const unsigned int x = hword[w];
        #pragma unroll
        for (int t = 0; t < 4; ++t)
            if (((x >> (t * 8)) & 0xFFu) < hj) mhi |= (1ULL << ((w - 16) * 4 + t));
    }

    // Nearest strictly-smaller left/right; (2ULL<<63)-1 wraps so j==63/127 fall
    // through correctly. The j<64 branch is wave-uniform.
    int left, right;
    if (j < 64) {
        const unsigned long long below = mlo & ((1ULL << j) - 1ULL);
        const unsigned long long above = mlo & ~((2ULL << j) - 1ULL);
        left  = below ? 63 - __builtin_clzll(below) : -1;
        right = above ? __builtin_ctzll(above)
                      : (mhi ? 64 + __builtin_ctzll(mhi) : W);
    } else {
        const int jj = j - 64;
        const unsigned long long below = mhi & ((1ULL << jj) - 1ULL);
        const unsigned long long above = mhi & ~((2ULL << jj) - 1ULL);
        left  = below ? 127 - __builtin_clzll(below)
                      : (mlo ? 63 - __builtin_clzll(mlo) : -1);
        right = above ? 64 + __builtin_ctzll(above) : W;
    }

    int area = (int)hj * (right - left - 1);

    #pragma unroll
    for (int off = 32; off > 0; off >>= 1)    // 64-lane wave max-reduce
        area = max(area, __shfl_xor(area, off, 64));
    if ((j & 63) == 0) wmax[j >> 6] = area;
    __syncthreads();
    if (j == 0) {
        const int m = max(wmax[0], wmax[1]);
        if (use_atomic) atomicMax(&out[b], m);    // fallback path only
        else partials[task] = m;                  // non-atomic, no contention
    }
}

// Phase 2: out[b] = max over 128 row-partials. Plain stores fully overwrite
// out every call (no memset, no atomics, no cross-call state).
__global__ __launch_bounds__(H) void lr_reduce(const int* __restrict__ partials,
                                               int* __restrict__ out) {
    const int b = blockIdx.x;
    const int j = threadIdx.x;
    __shared__ int wm[2];
    int v = partials[b * H + j];              // coalesced 512B per block
    #pragma unroll
    for (int off = 32; off > 0; off >>= 1)
        v = max(v, __shfl_xor(v, off, 64));
    if ((j & 63) == 0) wm[j >> 6] = v;
    __syncthreads();
    if (j == 0) out[b] = max(wm[0], wm[1]);
}

extern "C" void kernel_launch(void* const* d_in, const int* in_sizes, int n_in,
                              void* d_out, int out_size, void* d_ws, size_t ws_size,
                              hipStream_t stream) {
    const float* Y = (const float*)d_in[0];
    int* out = (int*)d_out;

    if (ws_size >= (size_t)(B * H) * sizeof(int)) {   // 16 KB of partials
        int* partials = (int*)d_ws;
        lr_rows<<<B * H, W, 0, stream>>>(Y, partials, out, 0);
        lr_reduce<<<B, H, 0, stream>>>(partials, out);
    } else {
        // Workspace too small: zero out, then contended-atomic fallback.
        hipMemsetAsync(out, 0, (size_t)out_size * sizeof(int), stream);
        lr_rows<<<B * H, W, 0, stream>>>(Y, nullptr, out, 1);
    }
}

// Round 5
// 13.311 us; speedup vs baseline: 4.7252x; 1.3345x over previous
//
#include <hip/hip_runtime.h>

static constexpr int H = 128;
static constexpr int W = 128;
static constexpr int B = 32;

// Phase 1: one block per (batch,row).
// Heights: 32 INDEPENDENT clamped window loads, h = ctz(~bits) (serial
// fallback only for runs >= 32; input data is fixed (jax key 0), never hit).
// "h[k] < h[j]" masks via ballot threshold table: for uniform t, ONE
// __ballot(h < t) yields a 64-lane slice of the compare matrix. Loop
// t = 1..blockmax(h) (~8-12 on this data), store slices in LDS, then each
// thread picks tbl[h_j] and gets left/right with clz/ctz. Replaces ~420
// per-thread VALU insts with ~130.
__global__ __launch_bounds__(W) void lr_rows(const float* __restrict__ Y,
                                             int* __restrict__ partials,
                                             int* __restrict__ out,
                                             int use_atomic) {
    const int task = blockIdx.x;              // task = b*H + r
    const int b = task >> 7;
    const int r = task & (H - 1);
    const int j = threadIdx.x;
    const int wid = j >> 6;                   // wave 0: cols 0-63, wave 1: 64-127
    const int lane = j & 63;
    const float* __restrict__ ycol = Y + (size_t)b * H * W + j;

    // ---- height of column j at row r ----
    unsigned int wmask = 0u;
    #pragma unroll
    for (int k = 0; k < 32; ++k) {
        int t = r - k; t = t < 0 ? 0 : t;     // clamped: all loads in-bounds
        if (ycol[(size_t)t * W] > 0.5f) wmask |= (1u << k);
    }
    if (r < 32) wmask &= (2u << r) - 1u;      // r=31: (2u<<31)-1 wraps to ~0u, no-op
    int h;
    if (wmask == 0xFFFFFFFFu) {               // run spans window (needs r>=31)
        h = 32;
        int t = r - 32;
        while (t >= 0 && ycol[(size_t)t * W] > 0.5f) { ++h; --t; }
    } else {
        h = __builtin_ctz(~wmask);
    }

    // ---- block max of h ----
    __shared__ unsigned long long tbl[H + 1][2];   // [threshold][wave-half]
    __shared__ int hmx[2];
    __shared__ int wmax[2];
    int hm = h;
    #pragma unroll
    for (int off = 32; off > 0; off >>= 1)
        hm = max(hm, __shfl_xor(hm, off, 64));
    if (lane == 0) { hmx[wid] = hm; tbl[0][wid] = 0ULL; }   // tbl[0]: h=0 pick (area=0 anyway)
    __syncthreads();
    const int hmax = max(hmx[0], hmx[1]);     // wave-uniform loop bound

    // ---- threshold mask table: tbl[t][w] = ballot over wave w of (h < t) ----
    for (int t = 1; t <= hmax; ++t) {
        const unsigned long long m = __ballot(h < t);
        if (lane == 0) tbl[t][wid] = m;       // wave-uniform value, 1-lane write
    }
    __syncthreads();

    // ---- pick my compare-mask slice and find nearest-smaller left/right ----
    const unsigned long long mlo = tbl[h][0];
    const unsigned long long mhi = tbl[h][1];

    // (2ULL<<j)-1 wraps to all-ones at j==63 so the boundary falls through
    // correctly; the j<64 branch is wave-uniform.
    int left, right;
    if (j < 64) {
        const unsigned long long below = mlo & ((1ULL << j) - 1ULL);
        const unsigned long long above = mlo & ~((2ULL << j) - 1ULL);
        left  = below ? 63 - __builtin_clzll(below) : -1;
        right = above ? __builtin_ctzll(above)
                      : (mhi ? 64 + __builtin_ctzll(mhi) : W);
    } else {
        const int jj = j - 64;
        const unsigned long long below = mhi & ((1ULL << jj) - 1ULL);
        const unsigned long long above = mhi & ~((2ULL << jj) - 1ULL);
        left  = below ? 127 - __builtin_clzll(below)
                      : (mlo ? 63 - __builtin_clzll(mlo) : -1);
        right = above ? 64 + __builtin_ctzll(above) : W;
    }

    int area = h * (right - left - 1);

    #pragma unroll
    for (int off = 32; off > 0; off >>= 1)    // 64-lane wave max-reduce
        area = max(area, __shfl_xor(area, off, 64));
    if (lane == 0) wmax[wid] = area;
    __syncthreads();
    if (j == 0) {
        const int m = max(wmax[0], wmax[1]);
        if (use_atomic) atomicMax(&out[b], m);    // ws-too-small fallback only
        else partials[task] = m;                  // non-atomic, no contention
    }
}

// Phase 2: out[b] = max over 128 row-partials. Plain stores fully overwrite
// out every call (no memset, no atomics, no cross-call state).
__global__ __launch_bounds__(H) void lr_reduce(const int* __restrict__ partials,
                                               int* __restrict__ out) {
    const int b = blockIdx.x;
    const int j = threadIdx.x;
    __shared__ int wm[2];
    int v = partials[b * H + j];              // coalesced 512B per block
    #pragma unroll
    for (int off = 32; off > 0; off >>= 1)
        v = max(v, __shfl_xor(v, off, 64));
    if ((j & 63) == 0) wm[j >> 6] = v;
    __syncthreads();
    if (j == 0) out[b] = max(wm[0], wm[1]);
}

extern "C" void kernel_launch(void* const* d_in, const int* in_sizes, int n_in,
                              void* d_out, int out_size, void* d_ws, size_t ws_size,
                              hipStream_t stream) {
    const float* Y = (const float*)d_in[0];
    int* out = (int*)d_out;

    if (ws_size >= (size_t)(B * H) * sizeof(int)) {   // 16 KB of partials
        int* partials = (int*)d_ws;
        lr_rows<<<B * H, W, 0, stream>>>(Y, partials, out, 0);
        lr_reduce<<<B, H, 0, stream>>>(partials, out);
    } else {
        // Workspace too small: zero out, then contended-atomic fallback.
        hipMemsetAsync(out, 0, (size_t)out_size * sizeof(int), stream);
        lr_rows<<<B * H, W, 0, stream>>>(Y, nullptr, out, 1);
    }
}